// Round 9
// baseline (224.326 us; speedup 1.0000x reference)
//
#include <hip/hip_runtime.h>
#include <hip/hip_bf16.h>

using u16 = unsigned short;
using u32 = unsigned int;

typedef __attribute__((ext_vector_type(8))) short s16x8;
typedef __attribute__((ext_vector_type(4))) short s16x4;
typedef __attribute__((ext_vector_type(8))) __bf16 bf16x8;
typedef __attribute__((ext_vector_type(4))) float f32x4;
typedef __attribute__((ext_vector_type(2))) unsigned u32x2;

static __device__ __forceinline__ u16 f2bf(float f) {
  u32 u = __builtin_bit_cast(u32, f);
  u32 r = u + 0x7FFFu + ((u >> 16) & 1u);
  return (u16)(r >> 16);
}

static __device__ __forceinline__ float bf2f(u16 b) {
  u32 u = ((u32)b) << 16;
  return __builtin_bit_cast(float, u);
}

// pack 2 f32 -> u32 of 2 bf16 via the library (compiler emits v_cvt_pk_bf16_f32)
static __device__ __forceinline__ u32 pk2bf(float lo, float hi) {
  __hip_bfloat162 h = __float22bfloat162_rn(make_float2(lo, hi));
  u32 r;
  __builtin_memcpy(&r, &h, 4);
  return r;
}

static __device__ __forceinline__ f32x4 mfma16(s16x8 a, s16x8 b, f32x4 c) {
  return __builtin_amdgcn_mfma_f32_16x16x32_bf16(
      __builtin_bit_cast(bf16x8, a), __builtin_bit_cast(bf16x8, b), c, 0, 0, 0);
}

#define GLOAD_LDS16(gp, lp)                                                    \
  __builtin_amdgcn_global_load_lds(                                            \
      (const __attribute__((address_space(1))) void*)(gp),                     \
      (__attribute__((address_space(3))) void*)(lp), 16, 0, 0)

// ---------------- f32 -> bf16 convert (vectorized) ----------------
__global__ __launch_bounds__(256) void k_cvt(const float* __restrict__ in,
                                             u16* __restrict__ out, int n) {
  int i = (blockIdx.x * 256 + threadIdx.x) * 8;
  if (i >= n) return;
  const float4 v0 = *(const float4*)(in + i);
  const float4 v1 = *(const float4*)(in + i + 4);
  s16x8 o;
  o[0] = f2bf(v0.x); o[1] = f2bf(v0.y); o[2] = f2bf(v0.z); o[3] = f2bf(v0.w);
  o[4] = f2bf(v1.x); o[5] = f2bf(v1.y); o[6] = f2bf(v1.z); o[7] = f2bf(v1.w);
  *(s16x8*)(out + i) = o;
}

// ------------- transpose + convert: src[K][N] f32 -> dst[N][K] bf16 -------------
__global__ __launch_bounds__(256) void k_transpose_cvt(const float* __restrict__ src,
                                                       u16* __restrict__ dst,
                                                       int K, int N) {
  __shared__ float tile[64][65];
  const int n0 = blockIdx.x * 64, k0 = blockIdx.y * 64;
  const int c = threadIdx.x & 63, r4 = threadIdx.x >> 6;
#pragma unroll
  for (int i = 0; i < 16; ++i) {
    int r = (i << 2) + r4;
    tile[r][c] = src[(k0 + r) * N + n0 + c];
  }
  __syncthreads();
#pragma unroll
  for (int i = 0; i < 16; ++i) {
    int r = (i << 2) + r4;
    dst[(n0 + r) * K + k0 + c] = f2bf(tile[c][r]);
  }
}

// ---------------- GEMM (QKV): C[M,N] = A[M,K] @ BT[N,K]^T, fused epilogue ----------------
template <int MODE>
__global__ __launch_bounds__(256) void k_gemm(
    const u16* __restrict__ A, const u16* __restrict__ BT,
    u16* __restrict__ qg, u16* __restrict__ kg, u16* __restrict__ vtg,
    float* __restrict__ cout, int M, int N, int K) {
  __shared__ __align__(16) u16 As[128 * 32];
  __shared__ __align__(16) u16 Bs[128 * 32];
  __shared__ __align__(16) u16 Ct[(MODE == 0) ? (128 * 132) : 8];
  const int t = threadIdx.x;
  const int lane = t & 63;
  const int w = t >> 6, wr = w >> 1, wc = w & 1;
  const int lrow = lane & 15, lkg = lane >> 4;
  const int m0 = blockIdx.y * 128, n0 = blockIdx.x * 128;

  const int ch1 = t + 256;
  const int ra0 = t >> 2, ca0 = (t & 3) << 3;
  const int ra1 = ch1 >> 2, ca1 = (ch1 & 3) << 3;
  const u16* gA0 = A + (m0 + ra0) * K + ca0;
  const u16* gA1 = A + (m0 + ra1) * K + ca1;
  const u16* gB0 = BT + (n0 + ra0) * K + ca0;
  const u16* gB1 = BT + (n0 + ra1) * K + ca1;
  u16* lA0 = &As[t * 8];
  u16* lA1 = &As[ch1 * 8];
  u16* lB0 = &Bs[t * 8];
  u16* lB1 = &Bs[ch1 * 8];

  f32x4 acc[4][4];
#pragma unroll
  for (int m = 0; m < 4; ++m)
#pragma unroll
    for (int n = 0; n < 4; ++n) acc[m][n] = (f32x4){0.f, 0.f, 0.f, 0.f};

  for (int k0 = 0; k0 < K; k0 += 32) {
    GLOAD_LDS16(gA0 + k0, lA0);
    GLOAD_LDS16(gA1 + k0, lA1);
    GLOAD_LDS16(gB0 + k0, lB0);
    GLOAD_LDS16(gB1 + k0, lB1);
    __syncthreads();
    s16x8 af[4], bfr[4];
#pragma unroll
    for (int m = 0; m < 4; ++m)
      af[m] = *(const s16x8*)&As[(wr * 64 + m * 16 + lrow) * 32 + lkg * 8];
#pragma unroll
    for (int n = 0; n < 4; ++n)
      bfr[n] = *(const s16x8*)&Bs[(wc * 64 + n * 16 + lrow) * 32 + lkg * 8];
#pragma unroll
    for (int m = 0; m < 4; ++m)
#pragma unroll
      for (int n = 0; n < 4; ++n) acc[m][n] = mfma16(af[m], bfr[n], acc[m][n]);
    __syncthreads();
  }

  if (MODE == 0) {
    const int part = n0 >> 10;  // block-uniform: 0=q, 1=k, 2=v
    const int b = m0 >> 11;
    const int tt0 = m0 & 2047;
    if (part < 2) {
#pragma unroll
      for (int m = 0; m < 4; ++m)
#pragma unroll
        for (int n = 0; n < 4; ++n)
#pragma unroll
          for (int r = 0; r < 4; ++r) {
            const int tl = wr * 64 + m * 16 + lkg * 4 + r;
            const int rem = (n0 & 1023) + wc * 64 + n * 16 + lrow;
            const int h = rem >> 6, d = rem & 63;
            const int bh = b * 16 + h;
            const float v = acc[m][n][r];
            if (part == 0)
              qg[(bh * 2048 + tt0 + tl) * 64 + d] = f2bf(v * 0.18033688f);
            else
              kg[(bh * 2048 + tt0 + tl) * 64 + d] = f2bf(v);
          }
    } else {
      // v: C^T via LDS, then contiguous vT-row stores
#pragma unroll
      for (int m = 0; m < 4; ++m)
#pragma unroll
        for (int n = 0; n < 4; ++n) {
          const int cl2 = wc * 64 + n * 16 + lrow;
          const int tl = wr * 64 + m * 16 + lkg * 4;
          s16x4 pk;
#pragma unroll
          for (int r = 0; r < 4; ++r) pk[r] = f2bf(acc[m][n][r]);
          *(s16x4*)&Ct[cl2 * 132 + tl] = pk;
        }
      __syncthreads();
      const long vrow0 = (long)b * 1024 + (n0 & 1023);
      const int cl = t >> 1;
      const int ch = (t & 1) << 6;
      const u16* csrc = &Ct[cl * 132 + ch];
      u16* vdst = vtg + (vrow0 + cl) * 2048 + tt0 + ch;
#pragma unroll
      for (int j = 0; j < 8; ++j) {
        const s16x4 a4 = *(const s16x4*)&csrc[j * 8];
        const s16x4 b4 = *(const s16x4*)&csrc[j * 8 + 4];
        s16x8 v8;
        v8[0] = a4[0]; v8[1] = a4[1]; v8[2] = a4[2]; v8[3] = a4[3];
        v8[4] = b4[0]; v8[5] = b4[1]; v8[6] = b4[2]; v8[7] = b4[3];
        *(s16x8*)&vdst[j * 8] = v8;
      }
    }
  } else {
#pragma unroll
    for (int m = 0; m < 4; ++m)
#pragma unroll
      for (int n = 0; n < 4; ++n)
#pragma unroll
        for (int r = 0; r < 4; ++r) {
          const int rg = m0 + wr * 64 + m * 16 + lkg * 4 + r;
          const int cg = n0 + wc * 64 + n * 16 + lrow;
          cout[rg * N + cg] = acc[m][n][r];
        }
  }
}

// ---------------- GEMM2 (proj): BM=64 x BN=128, f32 out ----------------
__global__ __launch_bounds__(256) void k_gemm2(const u16* __restrict__ A,
                                               const u16* __restrict__ BT,
                                               float* __restrict__ cout, int M,
                                               int N, int K) {
  __shared__ __align__(16) u16 As[64 * 32];
  __shared__ __align__(16) u16 Bs[128 * 32];
  const int t = threadIdx.x;
  const int lane = t & 63;
  const int w = t >> 6, wr = w >> 1, wc = w & 1;
  const int lrow = lane & 15, lkg = lane >> 4;
  const int m0 = blockIdx.y * 64, n0 = blockIdx.x * 128;

  const int ra = t >> 2, ca = (t & 3) << 3;
  const u16* gA = A + (m0 + ra) * K + ca;
  const u16* gB0 = BT + (n0 + ra) * K + ca;
  const u16* gB1 = BT + (n0 + 64 + ra) * K + ca;
  u16* lA = &As[t * 8];
  u16* lB0 = &Bs[t * 8];
  u16* lB1 = &Bs[(t + 256) * 8];

  f32x4 acc[2][4];
#pragma unroll
  for (int m = 0; m < 2; ++m)
#pragma unroll
    for (int n = 0; n < 4; ++n) acc[m][n] = (f32x4){0.f, 0.f, 0.f, 0.f};

  for (int k0 = 0; k0 < K; k0 += 32) {
    GLOAD_LDS16(gA + k0, lA);
    GLOAD_LDS16(gB0 + k0, lB0);
    GLOAD_LDS16(gB1 + k0, lB1);
    __syncthreads();
    s16x8 af[2], bfr[4];
#pragma unroll
    for (int m = 0; m < 2; ++m)
      af[m] = *(const s16x8*)&As[(wr * 32 + m * 16 + lrow) * 32 + lkg * 8];
#pragma unroll
    for (int n = 0; n < 4; ++n)
      bfr[n] = *(const s16x8*)&Bs[(wc * 64 + n * 16 + lrow) * 32 + lkg * 8];
#pragma unroll
    for (int m = 0; m < 2; ++m)
#pragma unroll
      for (int n = 0; n < 4; ++n) acc[m][n] = mfma16(af[m], bfr[n], acc[m][n]);
    __syncthreads();
  }

#pragma unroll
  for (int m = 0; m < 2; ++m)
#pragma unroll
    for (int n = 0; n < 4; ++n)
#pragma unroll
      for (int r = 0; r < 4; ++r) {
        const int rg = m0 + wr * 32 + m * 16 + lkg * 4 + r;
        const int cg = n0 + wc * 64 + n * 16 + lrow;
        cout[rg * N + cg] = acc[m][n][r];
      }
}

// ---------------- causal flash attention, KV-split partial (v7) ----------------
// Block (qs, h) processes KV tiles [h?(qs+1):0, h?(2qs+2):(qs+1)).
// Stores UNNORMALIZED O (bf16) + per-row max m and denom os (f32).
__global__ __launch_bounds__(256) void k_attn_part(
    const u16* __restrict__ qg, const u16* __restrict__ kg,
    const u16* __restrict__ vtg, u16* __restrict__ Om,
    float* __restrict__ ms, float* __restrict__ osv) {
  __shared__ __align__(16) u16 Ks[2][64 * 64];
  __shared__ __align__(16) u16 Vs[2][64 * 64];
  __shared__ __align__(16) u16 Ps[4][32 * 72];
  const int t = threadIdx.x;
  const int lane = t & 63, w = t >> 6;
  const int lrow = lane & 15, lkg = lane >> 4;
  const int bx = blockIdx.x, by = blockIdx.y;
  const int hsplit = bx >> 4;
  const int qr = bx & 15;
  const int qs = (by & 16) ? (15 - qr) : qr;  // long+short pair per CU
  const int bh = by;
  const int qw0 = qs * 128 + w * 32;
  const int sw = lrow & 7;
  const f32x4 z4 = {0.f, 0.f, 0.f, 0.f};
  const s16x8 ones8 = {0x3F80, 0x3F80, 0x3F80, 0x3F80,
                       0x3F80, 0x3F80, 0x3F80, 0x3F80};  // bf16 1.0

  const u16* kbase = kg + ((long)bh << 11) * 64;
  const u16* vbase = vtg + ((long)bh << 6) * 2048;

  const int srow = lane >> 3;
  const int sxor8 = ((lane & 7) ^ srow) << 3;

  // Q fragments (pre-scaled by 1/8*log2e); used as MFMA B-operand
  s16x8 aq[2][2];
#pragma unroll
  for (int m = 0; m < 2; ++m)
#pragma unroll
    for (int kk = 0; kk < 2; ++kk)
      aq[m][kk] = *(const s16x8*)&qg[((bh << 11) + qw0 + m * 16 + lrow) * 64 +
                                     kk * 32 + lkg * 8];

  f32x4 o[2][4];   // O^T: lane holds O[q=qw0+16m+lrow][d=16d4+4lkg+r]
  f32x4 os[2];     // denominator carried in accumulator
  float mst[2];
#pragma unroll
  for (int m = 0; m < 2; ++m) {
#pragma unroll
    for (int d = 0; d < 4; ++d) o[m][d] = z4;
    os[m] = z4;
    mst[m] = -3e38f;
  }

  const int t0 = hsplit ? (qs + 1) : 0;
  const int t1 = hsplit ? (2 * qs + 2) : (qs + 1);

#define STAGE(BUF, TT)                                                         \
  {                                                                            \
    const int kv0s = (TT) << 6;                                                \
    _Pragma("unroll") for (int i = 0; i < 2; ++i) {                            \
      const int rr = ((i * 4 + w) << 3) + srow;                                \
      const int dst = (((i * 4 + w) << 6) + lane) << 3;                        \
      GLOAD_LDS16(kbase + ((kv0s + rr) << 6) + sxor8, &Ks[BUF][dst]);          \
      GLOAD_LDS16(vbase + ((long)rr << 11) + kv0s + sxor8, &Vs[BUF][dst]);     \
    }                                                                          \
  }

  STAGE(0, t0);
  int buf = 0;
  for (int tt = t0; tt < t1; ++tt) {
    const int kv0 = tt << 6;
    if (tt + 1 < t1) {
      STAGE(buf ^ 1, tt + 1);
      asm volatile("s_waitcnt vmcnt(4)" ::: "memory");
    } else {
      asm volatile("s_waitcnt vmcnt(0)" ::: "memory");
    }
    __builtin_amdgcn_s_barrier();
    __builtin_amdgcn_sched_barrier(0);

    if (kv0 < qw0 + 32) {
      // ---- S^T = K Q^T ----
      f32x4 s[2][4];
      __builtin_amdgcn_s_setprio(1);
#pragma unroll
      for (int c = 0; c < 4; ++c) {
        const int krow = c * 16 + lrow;
        s16x8 bk0 = *(const s16x8*)&Ks[buf][krow * 64 + ((lkg ^ sw) << 3)];
        s16x8 bk1 = *(const s16x8*)&Ks[buf][krow * 64 + (((4 + lkg) ^ sw) << 3)];
#pragma unroll
        for (int m = 0; m < 2; ++m)
          s[m][c] = mfma16(bk1, aq[m][1], mfma16(bk0, aq[m][0], z4));
      }
      __builtin_amdgcn_s_setprio(0);

      if (kv0 + 64 > qw0) {  // tile touches the diagonal: causal mask
#pragma unroll
        for (int m = 0; m < 2; ++m) {
          const int qrow = qw0 + m * 16 + lrow;
#pragma unroll
          for (int c = 0; c < 4; ++c) {
            const int kvb = kv0 + c * 16 + lkg * 4;
#pragma unroll
            for (int r = 0; r < 4; ++r)
              if (kvb + r > qrow) s[m][c][r] = -3e38f;
          }
        }
      }

      // ---- online softmax: lane-local row, shfl max-combine, pack P ----
      u16* PW = Ps[w];
#pragma unroll
      for (int m = 0; m < 2; ++m) {
        float lm = s[m][0][0];
#pragma unroll
        for (int c = 0; c < 4; ++c)
#pragma unroll
          for (int r = 0; r < 4; ++r) lm = fmaxf(lm, s[m][c][r]);
        lm = fmaxf(lm, __shfl_xor(lm, 16));
        lm = fmaxf(lm, __shfl_xor(lm, 32));
        const float mn = fmaxf(mst[m], lm);
        const float alm = exp2f(mst[m] - mn);
        mst[m] = mn;
#pragma unroll
        for (int d = 0; d < 4; ++d) o[m][d] *= alm;
        os[m] *= alm;
#pragma unroll
        for (int c = 0; c < 4; ++c) {
          const float p0 = exp2f(s[m][c][0] - mn);
          const float p1 = exp2f(s[m][c][1] - mn);
          const float p2 = exp2f(s[m][c][2] - mn);
          const float p3 = exp2f(s[m][c][3] - mn);
          const s16x4 pk4 =
              __builtin_bit_cast(s16x4, (u32x2){pk2bf(p0, p1), pk2bf(p2, p3)});
          *(s16x4*)&PW[(m * 16 + lrow) * 72 + c * 16 + lkg * 4] = pk4;
        }
      }

      // ---- B-fragments of P ----
      s16x8 pb[2][2];
#pragma unroll
      for (int m = 0; m < 2; ++m)
#pragma unroll
        for (int kk = 0; kk < 2; ++kk)
          pb[m][kk] =
              *(const s16x8*)&PW[(m * 16 + lrow) * 72 + kk * 32 + lkg * 8];

      // ---- O^T += V^T P^T ; denominator via ones-row MFMA ----
      __builtin_amdgcn_s_setprio(1);
#pragma unroll
      for (int d = 0; d < 4; ++d) {
        const int vrow = d * 16 + lrow;
        s16x8 bv0 = *(const s16x8*)&Vs[buf][vrow * 64 + ((lkg ^ sw) << 3)];
        s16x8 bv1 = *(const s16x8*)&Vs[buf][vrow * 64 + (((4 + lkg) ^ sw) << 3)];
#pragma unroll
        for (int m = 0; m < 2; ++m)
          o[m][d] = mfma16(bv1, pb[m][1], mfma16(bv0, pb[m][0], o[m][d]));
      }
#pragma unroll
      for (int m = 0; m < 2; ++m)
        os[m] = mfma16(ones8, pb[m][1], mfma16(ones8, pb[m][0], os[m]));
      __builtin_amdgcn_s_setprio(0);
    }

    __builtin_amdgcn_s_barrier();
    buf ^= 1;
  }

  // ---- store partial: unnormalized O (bf16), m/os (f32) ----
  const long rbase = ((long)(hsplit << 5) + bh) * 2048;
#pragma unroll
  for (int m = 0; m < 2; ++m) {
    const int q = qw0 + m * 16 + lrow;
    const long row = rbase + q;
    u16* orow = Om + row * 64;
#pragma unroll
    for (int d = 0; d < 4; ++d) {
      const s16x4 pk4 = __builtin_bit_cast(
          s16x4, (u32x2){pk2bf(o[m][d][0], o[m][d][1]),
                         pk2bf(o[m][d][2], o[m][d][3])});
      *(s16x4*)&orow[d * 16 + lkg * 4] = pk4;
    }
    if (lkg == 0) {
      ms[row] = mst[m];
      osv[row] = os[m][0];
    }
  }
#undef STAGE
}

// ---------------- combine partials -> yb (bf16) ----------------
__global__ __launch_bounds__(256) void k_attn_comb(const u16* __restrict__ Om,
                                                   const float* __restrict__ ms,
                                                   const float* __restrict__ osv,
                                                   u16* __restrict__ yb) {
  const int gid = blockIdx.x * 256 + threadIdx.x;  // 32*2048*8 total
  const int row = gid >> 3;                        // bh*2048 + q
  const int d0 = (gid & 7) << 3;
  const float mA = ms[row], mB = ms[65536 + row];
  const float oA = osv[row], oB = osv[65536 + row];
  const float M = fmaxf(mA, mB);
  const float wA = exp2f(mA - M), wB = exp2f(mB - M);
  const float inv = 1.0f / (wA * oA + wB * oB);
  const float sA = wA * inv, sB = wB * inv;
  const s16x8 a8 = *(const s16x8*)&Om[(long)row * 64 + d0];
  const s16x8 b8 = *(const s16x8*)&Om[((long)row + 65536) * 64 + d0];
  const int bh = row >> 11, q = row & 2047;
  const int b = bh >> 4, hh = bh & 15;
  u16* dst = yb + ((long)((b << 11) + q)) * 1024 + hh * 64 + d0;
  s16x8 y8;
#pragma unroll
  for (int j = 0; j < 8; ++j)
    y8[j] = f2bf(sA * bf2f((u16)a8[j]) + sB * bf2f((u16)b8[j]));
  *(s16x8*)dst = y8;
}

extern "C" void kernel_launch(void* const* d_in, const int* in_sizes, int n_in,
                              void* d_out, int out_size, void* d_ws,
                              size_t ws_size, hipStream_t stream) {
  const float* x = (const float*)d_in[0];
  const float* wa = (const float*)d_in[1];
  const float* wp = (const float*)d_in[2];
  float* out = (float*)d_out;
  u16* ws = (u16*)d_ws;

  u16* xb = ws;                 // [4096][1024]
  u16* wat = xb + 4194304;      // [3072][1024]
  u16* wpt = wat + 3145728;     // [1024][1024]
  u16* qg = wpt + 1048576;      // [32][2048][64]
  u16* kg = qg + 4194304;       // [32][2048][64]
  u16* vtg = kg + 4194304;      // [32][64][2048]
  u16* yb = vtg + 4194304;      // [4096][1024]
  u16* Om = yb + 4194304;       // [2][32][2048][64] bf16 partial O
  float* ms = (float*)(Om + 8388608);   // [2][32][2048]
  float* osv = ms + 131072;             // [2][32][2048]

  k_cvt<<<2048, 256, 0, stream>>>(x, xb, 4194304);
  k_transpose_cvt<<<dim3(48, 16), 256, 0, stream>>>(wa, wat, 1024, 3072);
  k_transpose_cvt<<<dim3(16, 16), 256, 0, stream>>>(wp, wpt, 1024, 1024);
  k_gemm<0><<<dim3(24, 32), 256, 0, stream>>>(xb, wat, qg, kg, vtg, nullptr,
                                              4096, 3072, 1024);
  k_attn_part<<<dim3(32, 32), 256, 0, stream>>>(qg, kg, vtg, Om, ms, osv);
  k_attn_comb<<<2048, 256, 0, stream>>>(Om, ms, osv, yb);
  k_gemm2<<<dim3(8, 64), 256, 0, stream>>>(yb, wpt, out, 4096, 1024, 1024);
}

// Round 11
// 214.637 us; speedup vs baseline: 1.0451x; 1.0451x over previous
//
#include <hip/hip_runtime.h>
#include <hip/hip_bf16.h>

using u16 = unsigned short;
using u32 = unsigned int;

typedef __attribute__((ext_vector_type(8))) short s16x8;
typedef __attribute__((ext_vector_type(4))) short s16x4;
typedef __attribute__((ext_vector_type(8))) __bf16 bf16x8;
typedef __attribute__((ext_vector_type(4))) float f32x4;
typedef __attribute__((ext_vector_type(2))) unsigned u32x2;

static __device__ __forceinline__ u16 f2bf(float f) {
  u32 u = __builtin_bit_cast(u32, f);
  u32 r = u + 0x7FFFu + ((u >> 16) & 1u);
  return (u16)(r >> 16);
}

// pack 2 f32 -> u32 of 2 bf16 via the library (compiler emits v_cvt_pk_bf16_f32)
static __device__ __forceinline__ u32 pk2bf(float lo, float hi) {
  __hip_bfloat162 h = __float22bfloat162_rn(make_float2(lo, hi));
  u32 r;
  __builtin_memcpy(&r, &h, 4);
  return r;
}

static __device__ __forceinline__ f32x4 mfma16(s16x8 a, s16x8 b, f32x4 c) {
  return __builtin_amdgcn_mfma_f32_16x16x32_bf16(
      __builtin_bit_cast(bf16x8, a), __builtin_bit_cast(bf16x8, b), c, 0, 0, 0);
}

#define GLOAD_LDS16(gp, lp)                                                    \
  __builtin_amdgcn_global_load_lds(                                            \
      (const __attribute__((address_space(1))) void*)(gp),                     \
      (__attribute__((address_space(3))) void*)(lp), 16, 0, 0)

// ---------------- f32 -> bf16 convert (vectorized) ----------------
__global__ __launch_bounds__(256) void k_cvt(const float* __restrict__ in,
                                             u16* __restrict__ out, int n) {
  int i = (blockIdx.x * 256 + threadIdx.x) * 8;
  if (i >= n) return;
  const float4 v0 = *(const float4*)(in + i);
  const float4 v1 = *(const float4*)(in + i + 4);
  s16x8 o;
  o[0] = f2bf(v0.x); o[1] = f2bf(v0.y); o[2] = f2bf(v0.z); o[3] = f2bf(v0.w);
  o[4] = f2bf(v1.x); o[5] = f2bf(v1.y); o[6] = f2bf(v1.z); o[7] = f2bf(v1.w);
  *(s16x8*)(out + i) = o;
}

// ------------- transpose + convert: src[K][N] f32 -> dst[N][K] bf16 -------------
__global__ __launch_bounds__(256) void k_transpose_cvt(const float* __restrict__ src,
                                                       u16* __restrict__ dst,
                                                       int K, int N) {
  __shared__ float tile[64][65];
  const int n0 = blockIdx.x * 64, k0 = blockIdx.y * 64;
  const int c = threadIdx.x & 63, r4 = threadIdx.x >> 6;
#pragma unroll
  for (int i = 0; i < 16; ++i) {
    int r = (i << 2) + r4;
    tile[r][c] = src[(k0 + r) * N + n0 + c];
  }
  __syncthreads();
#pragma unroll
  for (int i = 0; i < 16; ++i) {
    int r = (i << 2) + r4;
    dst[(n0 + r) * K + k0 + c] = f2bf(tile[c][r]);
  }
}

// ---------------- GEMM (QKV): C[M,N] = A[M,K] @ BT[N,K]^T, fused epilogue ----------------
// MODE 0: all three parts (q/k/v) route the 128x128 C-tile through LDS so
// global stores are wide & coalesced. Ct UNIONS with As/Bs (staging is dead
// after the last K-iteration barrier) -> 34.8KB LDS, 4 blocks/CU.
// MODE 1: plain f32 C store (staging-only LDS).
template <int MODE>
__global__ __launch_bounds__(256) void k_gemm(
    const u16* __restrict__ A, const u16* __restrict__ BT,
    u16* __restrict__ qg, u16* __restrict__ kg, u16* __restrict__ vtg,
    float* __restrict__ cout, int M, int N, int K) {
  __shared__ __align__(16) u16 Sh[(MODE == 0) ? (128 * 136) : 8192];
  u16* As = Sh;          // [128*32]
  u16* Bs = Sh + 4096;   // [128*32]
  u16* Ct = Sh;          // epilogue reuse (after final barrier)
  const int t = threadIdx.x;
  const int lane = t & 63;
  const int w = t >> 6, wr = w >> 1, wc = w & 1;
  const int lrow = lane & 15, lkg = lane >> 4;
  const int m0 = blockIdx.y * 128, n0 = blockIdx.x * 128;

  const int ch1 = t + 256;
  const int ra0 = t >> 2, ca0 = (t & 3) << 3;
  const int ra1 = ch1 >> 2, ca1 = (ch1 & 3) << 3;
  const u16* gA0 = A + (m0 + ra0) * K + ca0;
  const u16* gA1 = A + (m0 + ra1) * K + ca1;
  const u16* gB0 = BT + (n0 + ra0) * K + ca0;
  const u16* gB1 = BT + (n0 + ra1) * K + ca1;
  u16* lA0 = &As[t * 8];
  u16* lA1 = &As[ch1 * 8];
  u16* lB0 = &Bs[t * 8];
  u16* lB1 = &Bs[ch1 * 8];

  f32x4 acc[4][4];
#pragma unroll
  for (int m = 0; m < 4; ++m)
#pragma unroll
    for (int n = 0; n < 4; ++n) acc[m][n] = (f32x4){0.f, 0.f, 0.f, 0.f};

  for (int k0 = 0; k0 < K; k0 += 32) {
    GLOAD_LDS16(gA0 + k0, lA0);
    GLOAD_LDS16(gA1 + k0, lA1);
    GLOAD_LDS16(gB0 + k0, lB0);
    GLOAD_LDS16(gB1 + k0, lB1);
    __syncthreads();
    s16x8 af[4], bfr[4];
#pragma unroll
    for (int m = 0; m < 4; ++m)
      af[m] = *(const s16x8*)&As[(wr * 64 + m * 16 + lrow) * 32 + lkg * 8];
#pragma unroll
    for (int n = 0; n < 4; ++n)
      bfr[n] = *(const s16x8*)&Bs[(wc * 64 + n * 16 + lrow) * 32 + lkg * 8];
#pragma unroll
    for (int m = 0; m < 4; ++m)
#pragma unroll
      for (int n = 0; n < 4; ++n) acc[m][n] = mfma16(af[m], bfr[n], acc[m][n]);
    __syncthreads();
  }

  if (MODE == 0) {
    const int part = n0 >> 10;  // block-uniform: 0=q, 1=k, 2=v
    const int b = m0 >> 11;
    const int tt0 = m0 & 2047;
    if (part < 2) {
      // q/k: C-tile -> Ct[t-local][d-local] (pad 136), then 256B-coalesced stores
      const float scale = (part == 0) ? 0.18033688f : 1.0f;  // 1/8*log2e for q
#pragma unroll
      for (int m = 0; m < 4; ++m)
#pragma unroll
        for (int n = 0; n < 4; ++n)
#pragma unroll
          for (int r = 0; r < 4; ++r)
            Ct[(wr * 64 + m * 16 + lkg * 4 + r) * 136 + wc * 64 + n * 16 +
               lrow] = f2bf(acc[m][n][r] * scale);
      __syncthreads();
      u16* dst0 = (part == 0) ? qg : kg;
      const int hbase = (b << 4) + ((n0 & 1023) >> 6);  // bh of col 0
#pragma unroll
      for (int it = 0; it < 8; ++it) {
        const int id = it * 256 + t;
        const int row = id >> 4;          // 0..127 (t-local)
        const int col = (id & 15) << 3;   // 0..120 (d-local, 8-elem chunk)
        const int h = hbase + (col >> 6);
        const int d = col & 63;
        *(s16x8*)&dst0[((long)h * 2048 + tt0 + row) * 64 + d] =
            *(const s16x8*)&Ct[row * 136 + col];
      }
    } else {
      // v: C^T via LDS, then contiguous vT-row stores
#pragma unroll
      for (int m = 0; m < 4; ++m)
#pragma unroll
        for (int n = 0; n < 4; ++n) {
          const int cl2 = wc * 64 + n * 16 + lrow;
          const int tl = wr * 64 + m * 16 + lkg * 4;
          s16x4 pk;
#pragma unroll
          for (int r = 0; r < 4; ++r) pk[r] = f2bf(acc[m][n][r]);
          *(s16x4*)&Ct[cl2 * 132 + tl] = pk;
        }
      __syncthreads();
      const long vrow0 = (long)b * 1024 + (n0 & 1023);
      const int cl = t >> 1;
      const int ch = (t & 1) << 6;
      const u16* csrc = &Ct[cl * 132 + ch];
      u16* vdst = vtg + (vrow0 + cl) * 2048 + tt0 + ch;
#pragma unroll
      for (int j = 0; j < 8; ++j) {
        const s16x4 a4 = *(const s16x4*)&csrc[j * 8];
        const s16x4 b4 = *(const s16x4*)&csrc[j * 8 + 4];
        s16x8 v8;
        v8[0] = a4[0]; v8[1] = a4[1]; v8[2] = a4[2]; v8[3] = a4[3];
        v8[4] = b4[0]; v8[5] = b4[1]; v8[6] = b4[2]; v8[7] = b4[3];
        *(s16x8*)&vdst[j * 8] = v8;
      }
    }
  } else {
#pragma unroll
    for (int m = 0; m < 4; ++m)
#pragma unroll
      for (int n = 0; n < 4; ++n)
#pragma unroll
        for (int r = 0; r < 4; ++r) {
          const int rg = m0 + wr * 64 + m * 16 + lkg * 4 + r;
          const int cg = n0 + wc * 64 + n * 16 + lrow;
          cout[rg * N + cg] = acc[m][n][r];
        }
  }
}

// ---------------- GEMM2 (proj): BM=64 x BN=128, f32 out ----------------
__global__ __launch_bounds__(256) void k_gemm2(const u16* __restrict__ A,
                                               const u16* __restrict__ BT,
                                               float* __restrict__ cout, int M,
                                               int N, int K) {
  __shared__ __align__(16) u16 As[64 * 32];
  __shared__ __align__(16) u16 Bs[128 * 32];
  const int t = threadIdx.x;
  const int lane = t & 63;
  const int w = t >> 6, wr = w >> 1, wc = w & 1;
  const int lrow = lane & 15, lkg = lane >> 4;
  const int m0 = blockIdx.y * 64, n0 = blockIdx.x * 128;

  const int ra = t >> 2, ca = (t & 3) << 3;
  const u16* gA = A + (m0 + ra) * K + ca;
  const u16* gB0 = BT + (n0 + ra) * K + ca;
  const u16* gB1 = BT + (n0 + 64 + ra) * K + ca;
  u16* lA = &As[t * 8];
  u16* lB0 = &Bs[t * 8];
  u16* lB1 = &Bs[(t + 256) * 8];

  f32x4 acc[2][4];
#pragma unroll
  for (int m = 0; m < 2; ++m)
#pragma unroll
    for (int n = 0; n < 4; ++n) acc[m][n] = (f32x4){0.f, 0.f, 0.f, 0.f};

  for (int k0 = 0; k0 < K; k0 += 32) {
    GLOAD_LDS16(gA + k0, lA);
    GLOAD_LDS16(gB0 + k0, lB0);
    GLOAD_LDS16(gB1 + k0, lB1);
    __syncthreads();
    s16x8 af[2], bfr[4];
#pragma unroll
    for (int m = 0; m < 2; ++m)
      af[m] = *(const s16x8*)&As[(wr * 32 + m * 16 + lrow) * 32 + lkg * 8];
#pragma unroll
    for (int n = 0; n < 4; ++n)
      bfr[n] = *(const s16x8*)&Bs[(wc * 64 + n * 16 + lrow) * 32 + lkg * 8];
#pragma unroll
    for (int m = 0; m < 2; ++m)
#pragma unroll
      for (int n = 0; n < 4; ++n) acc[m][n] = mfma16(af[m], bfr[n], acc[m][n]);
    __syncthreads();
  }

#pragma unroll
  for (int m = 0; m < 2; ++m)
#pragma unroll
    for (int n = 0; n < 4; ++n)
#pragma unroll
      for (int r = 0; r < 4; ++r) {
        const int rg = m0 + wr * 32 + m * 16 + lkg * 4 + r;
        const int cg = n0 + wc * 64 + n * 16 + lrow;
        cout[rg * N + cg] = acc[m][n][r];
      }
}

// ---------------- causal flash attention (R8 verbatim — known good, 75us) ----------------
__global__ __launch_bounds__(256) void k_attn(const u16* __restrict__ qg,
                                              const u16* __restrict__ kg,
                                              const u16* __restrict__ vtg,
                                              u16* __restrict__ yb) {
  __shared__ __align__(16) u16 Ks[2][64 * 64];
  __shared__ __align__(16) u16 Vs[2][64 * 64];
  __shared__ __align__(16) u16 Ps[4][32 * 72];
  const int t = threadIdx.x;
  const int lane = t & 63, w = t >> 6;
  const int lrow = lane & 15, lkg = lane >> 4;
  const int bx = blockIdx.x, by = blockIdx.y;
  const int qs = (by & 16) ? (15 - bx) : bx;  // long+short pair per CU
  const int bh = by;
  const int qw0 = qs * 128 + w * 32;
  const int hb = bh & 15, bb = bh >> 4;
  const int sw = lrow & 7;
  const f32x4 z4 = {0.f, 0.f, 0.f, 0.f};
  const s16x8 ones8 = {0x3F80, 0x3F80, 0x3F80, 0x3F80,
                       0x3F80, 0x3F80, 0x3F80, 0x3F80};  // bf16 1.0

  const u16* kbase = kg + ((long)bh << 11) * 64;
  const u16* vbase = vtg + ((long)bh << 6) * 2048;

  const int srow = lane >> 3;
  const int sxor8 = ((lane & 7) ^ srow) << 3;

  // Q fragments (pre-scaled by 1/8*log2e); used as MFMA B-operand
  s16x8 aq[2][2];
#pragma unroll
  for (int m = 0; m < 2; ++m)
#pragma unroll
    for (int kk = 0; kk < 2; ++kk)
      aq[m][kk] = *(const s16x8*)&qg[((bh << 11) + qw0 + m * 16 + lrow) * 64 +
                                     kk * 32 + lkg * 8];

  f32x4 o[2][4];   // O^T: lane holds O[q=qw0+16m+lrow][d=16d4+4lkg+r]
  f32x4 os[2];     // denominator carried in accumulator (all r identical)
  float mst[2];
#pragma unroll
  for (int m = 0; m < 2; ++m) {
#pragma unroll
    for (int d = 0; d < 4; ++d) o[m][d] = z4;
    os[m] = z4;
    mst[m] = -3e38f;
  }

  const int nt = 2 * qs + 2;

#define STAGE(BUF, TT)                                                         \
  {                                                                            \
    const int kv0s = (TT) << 6;                                                \
    _Pragma("unroll") for (int i = 0; i < 2; ++i) {                            \
      const int rr = ((i * 4 + w) << 3) + srow;                                \
      const int dst = (((i * 4 + w) << 6) + lane) << 3;                        \
      GLOAD_LDS16(kbase + ((kv0s + rr) << 6) + sxor8, &Ks[BUF][dst]);          \
      GLOAD_LDS16(vbase + ((long)rr << 11) + kv0s + sxor8, &Vs[BUF][dst]);     \
    }                                                                          \
  }

  STAGE(0, 0);
  int buf = 0;
  for (int tt = 0; tt < nt; ++tt) {
    const int kv0 = tt << 6;
    if (tt + 1 < nt) {
      STAGE(buf ^ 1, tt + 1);
      asm volatile("s_waitcnt vmcnt(4)" ::: "memory");
    } else {
      asm volatile("s_waitcnt vmcnt(0)" ::: "memory");
    }
    __builtin_amdgcn_s_barrier();
    __builtin_amdgcn_sched_barrier(0);

    if (kv0 < qw0 + 32) {
      // ---- S^T = K Q^T : s[m][c][r] = S[q=qw0+16m+lrow][kv=kv0+16c+4lkg+r] ----
      f32x4 s[2][4];
      __builtin_amdgcn_s_setprio(1);
#pragma unroll
      for (int c = 0; c < 4; ++c) {
        const int krow = c * 16 + lrow;
        s16x8 bk0 = *(const s16x8*)&Ks[buf][krow * 64 + ((lkg ^ sw) << 3)];
        s16x8 bk1 = *(const s16x8*)&Ks[buf][krow * 64 + (((4 + lkg) ^ sw) << 3)];
#pragma unroll
        for (int m = 0; m < 2; ++m)
          s[m][c] = mfma16(bk1, aq[m][1], mfma16(bk0, aq[m][0], z4));
      }
      __builtin_amdgcn_s_setprio(0);

      if (kv0 + 64 > qw0) {  // tile touches the diagonal: causal mask
#pragma unroll
        for (int m = 0; m < 2; ++m) {
          const int qrow = qw0 + m * 16 + lrow;
#pragma unroll
          for (int c = 0; c < 4; ++c) {
            const int kvb = kv0 + c * 16 + lkg * 4;
#pragma unroll
            for (int r = 0; r < 4; ++r)
              if (kvb + r > qrow) s[m][c][r] = -3e38f;
          }
        }
      }

      // ---- online softmax: lane-local row, shfl max-combine, pack P ----
      u16* PW = Ps[w];
#pragma unroll
      for (int m = 0; m < 2; ++m) {
        float lm = s[m][0][0];
#pragma unroll
        for (int c = 0; c < 4; ++c)
#pragma unroll
          for (int r = 0; r < 4; ++r) lm = fmaxf(lm, s[m][c][r]);
        lm = fmaxf(lm, __shfl_xor(lm, 16));
        lm = fmaxf(lm, __shfl_xor(lm, 32));
        const float mn = fmaxf(mst[m], lm);
        const float alm = exp2f(mst[m] - mn);
        mst[m] = mn;
#pragma unroll
        for (int d = 0; d < 4; ++d) o[m][d] *= alm;
        os[m] *= alm;
#pragma unroll
        for (int c = 0; c < 4; ++c) {
          const float p0 = exp2f(s[m][c][0] - mn);
          const float p1 = exp2f(s[m][c][1] - mn);
          const float p2 = exp2f(s[m][c][2] - mn);
          const float p3 = exp2f(s[m][c][3] - mn);
          const s16x4 pk4 =
              __builtin_bit_cast(s16x4, (u32x2){pk2bf(p0, p1), pk2bf(p2, p3)});
          *(s16x4*)&PW[(m * 16 + lrow) * 72 + c * 16 + lkg * 4] = pk4;
        }
      }

      // ---- B-fragments of P: contiguous b128 reads ----
      s16x8 pb[2][2];
#pragma unroll
      for (int m = 0; m < 2; ++m)
#pragma unroll
        for (int kk = 0; kk < 2; ++kk)
          pb[m][kk] =
              *(const s16x8*)&PW[(m * 16 + lrow) * 72 + kk * 32 + lkg * 8];

      // ---- O^T += V^T P^T ; denominator via ones-row MFMA ----
      __builtin_amdgcn_s_setprio(1);
#pragma unroll
      for (int d = 0; d < 4; ++d) {
        const int vrow = d * 16 + lrow;
        s16x8 bv0 = *(const s16x8*)&Vs[buf][vrow * 64 + ((lkg ^ sw) << 3)];
        s16x8 bv1 = *(const s16x8*)&Vs[buf][vrow * 64 + (((4 + lkg) ^ sw) << 3)];
#pragma unroll
        for (int m = 0; m < 2; ++m)
          o[m][d] = mfma16(bv1, pb[m][1], mfma16(bv0, pb[m][0], o[m][d]));
      }
#pragma unroll
      for (int m = 0; m < 2; ++m)
        os[m] = mfma16(ones8, pb[m][1], mfma16(ones8, pb[m][0], os[m]));
      __builtin_amdgcn_s_setprio(0);
    }

    __builtin_amdgcn_s_barrier();
    buf ^= 1;
  }

  // ---- normalize + store: 4-contig d per (m,d4) -> 8B stores ----
#pragma unroll
  for (int m = 0; m < 2; ++m) {
    const float inv = 1.0f / os[m][0];
    const int q = qw0 + m * 16 + lrow;
    u16* yrow = yb + ((long)((bb << 11) + q)) * 1024 + hb * 64;
#pragma unroll
    for (int d = 0; d < 4; ++d) {
      const s16x4 pk4 = __builtin_bit_cast(
          s16x4, (u32x2){pk2bf(o[m][d][0] * inv, o[m][d][1] * inv),
                         pk2bf(o[m][d][2] * inv, o[m][d][3] * inv)});
      *(s16x4*)&yrow[d * 16 + lkg * 4] = pk4;
    }
  }
#undef STAGE
}

extern "C" void kernel_launch(void* const* d_in, const int* in_sizes, int n_in,
                              void* d_out, int out_size, void* d_ws,
                              size_t ws_size, hipStream_t stream) {
  const float* x = (const float*)d_in[0];
  const float* wa = (const float*)d_in[1];
  const float* wp = (const float*)d_in[2];
  float* out = (float*)d_out;
  u16* ws = (u16*)d_ws;

  u16* xb = ws;                 // [4096][1024]
  u16* wat = xb + 4194304;      // [3072][1024]
  u16* wpt = wat + 3145728;     // [1024][1024]
  u16* qg = wpt + 1048576;      // [32][2048][64]
  u16* kg = qg + 4194304;       // [32][2048][64]
  u16* vtg = kg + 4194304;      // [32][64][2048]
  u16* yb = vtg + 4194304;      // [4096][1024]

  k_cvt<<<2048, 256, 0, stream>>>(x, xb, 4194304);
  k_transpose_cvt<<<dim3(48, 16), 256, 0, stream>>>(wa, wat, 1024, 3072);
  k_transpose_cvt<<<dim3(16, 16), 256, 0, stream>>>(wp, wpt, 1024, 1024);
  k_gemm<0><<<dim3(24, 32), 256, 0, stream>>>(xb, wat, qg, kg, vtg, nullptr,
                                              4096, 3072, 1024);
  k_attn<<<dim3(16, 32), 256, 0, stream>>>(qg, kg, vtg, yb);
  k_gemm2<<<dim3(8, 64), 256, 0, stream>>>(yb, wpt, out, 4096, 1024, 1024);
}